// Round 1
// baseline (244.595 us; speedup 1.0000x reference)
//
#include <hip/hip_runtime.h>
#include <stdint.h>

// MultiHeadAttention2d: x,pe [16][512][1024] f32; W [1536][512]; b [1536]
// out = (x+pe) + MHA(x+pe); 8 heads, dim=64, N=1024.
// Pipeline: k_conv (W->bf16) ; k_addt (residual + s^T bf16) ;
//           k_gemm (QKV, two orientations) ; k_attn (flash attn + residual add)

typedef __attribute__((ext_vector_type(4))) float f32x4;
typedef __attribute__((ext_vector_type(8))) __bf16 bf16x8;
typedef __attribute__((ext_vector_type(8))) short short8;
typedef __attribute__((ext_vector_type(4))) short short4v;

#define DEVINL static __device__ __forceinline__

DEVINL unsigned short f2bf(float f) {  // RNE f32 -> bf16 bits
  unsigned u = __builtin_bit_cast(unsigned, f);
  u += 0x7FFFu + ((u >> 16) & 1u);
  return (unsigned short)(u >> 16);
}

DEVINL void gload16(const void* g, const void* lds) {  // async global->LDS, 16B/lane
  __builtin_amdgcn_global_load_lds(
      (const __attribute__((address_space(1))) unsigned int*)(uintptr_t)g,
      (__attribute__((address_space(3))) unsigned int*)(uintptr_t)lds, 16, 0, 0);
}

template <int CTRL>
DEVINL float dppmax(float x) {  // fmax with DPP-permuted self (VALU pipe)
  int yi = __builtin_amdgcn_update_dpp(0, __builtin_bit_cast(int, x), CTRL, 0xF, 0xF, true);
  return fmaxf(x, __builtin_bit_cast(float, yi));
}
DEVINL float rowmax16(float x) {  // max across each 16-lane DPP row
  x = dppmax<0xB1>(x);    // quad_perm [1,0,3,2]  (xor 1)
  x = dppmax<0x4E>(x);    // quad_perm [2,3,0,1]  (xor 2)
  x = dppmax<0x141>(x);   // row_half_mirror      (pairs quads)
  x = dppmax<0x140>(x);   // row_mirror           (pairs octets)
  return x;
}

// ---------------- k_conv: W f32 -> bf16 ----------------
__global__ __launch_bounds__(256) void k_conv(const float* __restrict__ Wf,
                                              unsigned short* __restrict__ wbo) {
  const int i = (blockIdx.x * 256 + threadIdx.x) * 4;
  const f32x4 v = *(const f32x4*)(Wf + i);
  short4v t;
  t[0] = (short)f2bf(v[0]); t[1] = (short)f2bf(v[1]);
  t[2] = (short)f2bf(v[2]); t[3] = (short)f2bf(v[3]);
  *(short4v*)(wbo + i) = t;
}

// ---------------- k_addt: s = x+pe -> out (f32) ; s^T bf16 [b][n][c] ----------------
__global__ __launch_bounds__(256) void k_addt(const float* __restrict__ x,
                                              const float* __restrict__ pe,
                                              float* __restrict__ out,
                                              unsigned short* __restrict__ st) {
  __shared__ unsigned short T[64][64];  // bf16 tile [c][n]
  const int b = blockIdx.z, ct = blockIdx.y, nt = blockIdx.x;
  const int tid = threadIdx.x;
  const int cl = tid >> 4, n4 = (tid & 15) * 4;
  const size_t base = ((size_t)b * 512 + ct * 64) * 1024 + nt * 64;
#pragma unroll
  for (int i = 0; i < 4; ++i) {
    const int c = cl + i * 16;
    const size_t idx = base + (size_t)c * 1024 + n4;
    const f32x4 xv = *(const f32x4*)(x + idx);
    const f32x4 pv = *(const f32x4*)(pe + idx);
    const f32x4 s = xv + pv;
    *(f32x4*)(out + idx) = s;  // residual, coalesced
    short4v t;
    t[0] = (short)f2bf(s[0]); t[1] = (short)f2bf(s[1]);
    t[2] = (short)f2bf(s[2]); t[3] = (short)f2bf(s[3]);
    *(short4v*)&T[c][n4] = t;
  }
  __syncthreads();
  const int nl = tid >> 2, cq = tid & 3;
  short8 v0, v1;
#pragma unroll
  for (int j = 0; j < 8; ++j) {
    v0[j] = (short)T[cq * 16 + j][nl];
    v1[j] = (short)T[cq * 16 + 8 + j][nl];
  }
  const size_t so = ((size_t)b * 1024 + nt * 64 + nl) * 512 + ct * 64 + cq * 16;
  *(short8*)(st + so) = v0;
  *(short8*)(st + so + 8) = v1;
}

// ---------------- k_gemm: QKV projection ----------------
// mode0 (blockIdx.y<8):  D = Out^T[n][o], A = s^T [n][c], B^T = W[o][c] (o in [0,1024))
//                        -> q,k stored [b][h][n][d]
// mode1 (blockIdx.y>=8): D = Out[o][n],  A = W[o][c] (o-1024 in [0,512)), B^T = s^T
//                        -> v stored [b][h][d][n]
__global__ __launch_bounds__(256, 2) void k_gemm(const unsigned short* __restrict__ st,
                                                 const unsigned short* __restrict__ wb,
                                                 const float* __restrict__ bias,
                                                 unsigned short* __restrict__ qb,
                                                 unsigned short* __restrict__ kb,
                                                 unsigned short* __restrict__ vb) {
  const int b = blockIdx.z;
  const int mode = (blockIdx.y >= 8);
  const int tile_m = (mode ? (blockIdx.y - 8) : blockIdx.y) * 128;
  const int tile_n = blockIdx.x * 128;
  const unsigned short* Ag;
  const unsigned short* Bg;
  if (!mode) {
    Ag = st + (size_t)b * 524288 + (size_t)tile_m * 512;
    Bg = wb + (size_t)tile_n * 512;
  } else {
    Ag = wb + (size_t)(1024 + tile_m) * 512;
    Bg = st + (size_t)b * 524288 + (size_t)tile_n * 512;
  }
  __shared__ unsigned short As[4096];  // [128][32] bf16
  __shared__ unsigned short Bs[4096];
  const int tid = threadIdx.x, lane = tid & 63, w = tid >> 6;
  const int wrow = w >> 1, wcol = w & 1, lr = lane & 15, g = lane >> 4;
  f32x4 acc[4][4] = {};
  for (int kt = 0; kt < 16; ++kt) {
    __syncthreads();
#pragma unroll
    for (int j = 0; j < 2; ++j) {
      const int D = j * 4096 + w * 1024 + lane * 16;
      const int row = D >> 6, off = D & 63;
      gload16((const char*)Ag + (size_t)row * 1024 + kt * 64 + off,
              (const char*)As + j * 4096 + w * 1024);
      gload16((const char*)Bg + (size_t)row * 1024 + kt * 64 + off,
              (const char*)Bs + j * 4096 + w * 1024);
    }
    __syncthreads();
    bf16x8 a[4], bb[4];
#pragma unroll
    for (int i = 0; i < 4; ++i) {
      a[i]  = *(const bf16x8*)(As + (wrow * 64 + i * 16 + lr) * 32 + g * 8);
      bb[i] = *(const bf16x8*)(Bs + (wcol * 64 + i * 16 + lr) * 32 + g * 8);
    }
#pragma unroll
    for (int i = 0; i < 4; ++i)
#pragma unroll
      for (int jj = 0; jj < 4; ++jj)
        acc[i][jj] = __builtin_amdgcn_mfma_f32_16x16x32_bf16(a[i], bb[jj], acc[i][jj], 0, 0, 0);
  }
  if (!mode) {
#pragma unroll
    for (int jj = 0; jj < 4; ++jj) {
      const int o = tile_n + wcol * 64 + jj * 16 + lr;
      const float bv = bias[o];
      unsigned short* dst = (o < 512) ? qb : kb;
      const size_t rowbase = ((size_t)b * 8 + ((o >> 6) & 7)) * 1024;
      const int d = o & 63;
#pragma unroll
      for (int i = 0; i < 4; ++i) {
        const int n0 = tile_m + wrow * 64 + i * 16 + g * 4;
#pragma unroll
        for (int r = 0; r < 4; ++r)
          dst[(rowbase + n0 + r) * 64 + d] = f2bf(acc[i][jj][r] + bv);
      }
    }
  } else {
#pragma unroll
    for (int i = 0; i < 4; ++i) {
#pragma unroll
      for (int r = 0; r < 4; ++r) {
        const int oh = tile_m + wrow * 64 + i * 16 + g * 4 + r;  // 0..511
        const float bv = bias[1024 + oh];
        const size_t rb = (((size_t)b * 8 + (oh >> 6)) * 64 + (oh & 63)) * 1024;
#pragma unroll
        for (int jj = 0; jj < 4; ++jj) {
          const int n = tile_n + wcol * 64 + jj * 16 + lr;
          vb[rb + n] = f2bf(acc[i][jj][r] + bv);
        }
      }
    }
  }
}

// ---------------- k_attn: flash attention + residual add ----------------
// block = (b,h) x 128-row q-tile; 4 waves x 32 q-rows; KV chunks of 64.
__global__ __launch_bounds__(256, 2) void k_attn(const unsigned short* __restrict__ qb,
                                                 const unsigned short* __restrict__ kb,
                                                 const unsigned short* __restrict__ vb,
                                                 float* __restrict__ out) {
  __shared__ __align__(16) char smem[64 * 132 * 4];  // 33792 B
  unsigned short* Ks = (unsigned short*)smem;        // [64 m][64 d] bf16, swizzled
  unsigned short* Vs = (unsigned short*)(smem + 8192);  // [64 d][64 m] bf16, swizzled
  char* Ps = smem + 16384;                           // per-wave [32 n][64 m] bf16, swizzled
  float* Os = (float*)smem;                          // epilogue: [64 d][132] f32

  const int qt = blockIdx.x, bh = blockIdx.y;
  const int tid = threadIdx.x, lane = tid & 63, w = tid >> 6;
  const int lr = lane & 15, g = lane >> 4;
  const float F = 0.18033688011112042f;  // (1/sqrt(64)) * log2(e)

  // Q fragments in registers: rows qt*128 + w*32 + ai*16 + lr
  const unsigned short* qrow = qb + ((size_t)bh * 1024 + qt * 128 + w * 32) * 64;
  bf16x8 qf[2][2];
#pragma unroll
  for (int ai = 0; ai < 2; ++ai)
#pragma unroll
    for (int ks = 0; ks < 2; ++ks)
      qf[ai][ks] = *(const bf16x8*)(qrow + (ai * 16 + lr) * 64 + ks * 32 + g * 8);

  f32x4 Oacc[2][4] = {};
  float mrow[2][4], lrow[2][4];
#pragma unroll
  for (int ai = 0; ai < 2; ++ai)
#pragma unroll
    for (int r = 0; r < 4; ++r) { mrow[ai][r] = -__builtin_inff(); lrow[ai][r] = 0.f; }

  bf16x8 ones;
#pragma unroll
  for (int j = 0; j < 8; ++j) ones[j] = (__bf16)1.0f;

  const char* kbase = (const char*)(kb + (size_t)bh * 65536);
  const char* vbase = (const char*)(vb + (size_t)bh * 65536);

  for (int mt = 0; mt < 16; ++mt) {
    __syncthreads();
    // Stage K [64][64] and V [64][64]; linear LDS dest, inverse-swizzled global src.
#pragma unroll
    for (int j = 0; j < 2; ++j) {
      const int D = j * 4096 + w * 1024 + lane * 16;
      const int row = D >> 7, ch = (D >> 4) & 7;
      const int sw = (ch ^ (row & 7)) * 16;
      gload16(kbase + (size_t)(mt * 64 + row) * 128 + sw, (const char*)Ks + j * 4096 + w * 1024);
      gload16(vbase + (size_t)row * 2048 + mt * 128 + sw, (const char*)Vs + j * 4096 + w * 1024);
    }
    __syncthreads();

    // S = Q K^T (raw, scale folded into exp2)
    f32x4 s[2][4] = {};
#pragma unroll
    for (int ks = 0; ks < 2; ++ks) {
      bf16x8 kf[4];
#pragma unroll
      for (int ct = 0; ct < 4; ++ct)
        kf[ct] = *(const bf16x8*)((const char*)Ks + (ct * 16 + lr) * 128 +
                                  ((ks * 64 + g * 16) ^ ((lr & 7) << 4)));
#pragma unroll
      for (int ai = 0; ai < 2; ++ai)
#pragma unroll
        for (int ct = 0; ct < 4; ++ct)
          s[ai][ct] = __builtin_amdgcn_mfma_f32_16x16x32_bf16(qf[ai][ks], kf[ct], s[ai][ct], 0, 0, 0);
    }

    // Online softmax: DPP row-max, rescale O, write P (bf16) to swizzled LDS.
    float alpha[2][4];
#pragma unroll
    for (int ai = 0; ai < 2; ++ai) {
#pragma unroll
      for (int r = 0; r < 4; ++r) {
        float tm = fmaxf(fmaxf(s[ai][0][r], s[ai][1][r]), fmaxf(s[ai][2][r], s[ai][3][r]));
        tm = rowmax16(tm);
        const float mn = fmaxf(mrow[ai][r], tm);
        alpha[ai][r] = __builtin_amdgcn_exp2f((mrow[ai][r] - mn) * F);
        mrow[ai][r] = mn;
        const int prow = ai * 16 + g * 4 + r;
#pragma unroll
        for (int ct = 0; ct < 4; ++ct) {
          const float p = __builtin_amdgcn_exp2f((s[ai][ct][r] - mn) * F);
          *(unsigned short*)(Ps + w * 4096 + prow * 128 +
                             ((ct * 32 + lr * 2) ^ ((prow & 7) << 4))) = f2bf(p);
        }
#pragma unroll
        for (int dt = 0; dt < 4; ++dt) Oacc[ai][dt][r] *= alpha[ai][r];
      }
    }

    // PV + row-sum (sum via MFMA against all-ones B-frag; every lane gets its rows' sums)
    f32x4 sacc[2] = {};
#pragma unroll
    for (int ks2 = 0; ks2 < 2; ++ks2) {
      bf16x8 pa[2];
#pragma unroll
      for (int ai = 0; ai < 2; ++ai) {
        pa[ai] = *(const bf16x8*)(Ps + w * 4096 + (ai * 16 + lr) * 128 +
                                  ((ks2 * 64 + g * 16) ^ ((lr & 7) << 4)));
        sacc[ai] = __builtin_amdgcn_mfma_f32_16x16x32_bf16(pa[ai], ones, sacc[ai], 0, 0, 0);
      }
#pragma unroll
      for (int dt = 0; dt < 4; ++dt) {
        const bf16x8 vf = *(const bf16x8*)((const char*)Vs + (dt * 16 + lr) * 128 +
                                           ((ks2 * 64 + g * 16) ^ ((lr & 7) << 4)));
#pragma unroll
        for (int ai = 0; ai < 2; ++ai)
          Oacc[ai][dt] = __builtin_amdgcn_mfma_f32_16x16x32_bf16(pa[ai], vf, Oacc[ai][dt], 0, 0, 0);
      }
    }
#pragma unroll
    for (int ai = 0; ai < 2; ++ai)
#pragma unroll
      for (int r = 0; r < 4; ++r)
        lrow[ai][r] = lrow[ai][r] * alpha[ai][r] + sacc[ai][r];
  }

  // Epilogue: O/l -> LDS transpose -> coalesced residual add into out[b][h*64+d][n]
  __syncthreads();
#pragma unroll
  for (int ai = 0; ai < 2; ++ai) {
#pragma unroll
    for (int r = 0; r < 4; ++r) {
      const float inv = 1.0f / lrow[ai][r];
#pragma unroll
      for (int dt = 0; dt < 4; ++dt)
        Os[(dt * 16 + lr) * 132 + (w * 32 + ai * 16 + g * 4 + r)] = Oacc[ai][dt][r] * inv;
    }
  }
  __syncthreads();
  const int d = tid >> 2, nq = tid & 3;
  float* orow = out + ((size_t)bh * 64 + d) * 1024 + qt * 128;
#pragma unroll
  for (int j = 0; j < 8; ++j) {
    const int n = nq * 32 + j * 4;
    const f32x4 ov = *(const f32x4*)(Os + d * 132 + n);
    const f32x4 cur = *(const f32x4*)(orow + n);
    *(f32x4*)(orow + n) = cur + ov;
  }
}

// ---------------- launcher ----------------
extern "C" void kernel_launch(void* const* d_in, const int* in_sizes, int n_in,
                              void* d_out, int out_size, void* d_ws, size_t ws_size,
                              hipStream_t stream) {
  const float* x    = (const float*)d_in[0];
  const float* pe   = (const float*)d_in[1];
  const float* W    = (const float*)d_in[2];
  const float* bias = (const float*)d_in[3];
  float* out = (float*)d_out;
  char* ws = (char*)d_ws;
  // ws layout (bytes): wb 0..1.5M, st @2M (16M), q @18M, k @34M, v @50M (16M each)
  unsigned short* wb = (unsigned short*)(ws);
  unsigned short* st = (unsigned short*)(ws + ((size_t)2 << 20));
  unsigned short* qb = (unsigned short*)(ws + ((size_t)18 << 20));
  unsigned short* kb = (unsigned short*)(ws + ((size_t)34 << 20));
  unsigned short* vb = (unsigned short*)(ws + ((size_t)50 << 20));

  k_conv<<<dim3(768), dim3(256), 0, stream>>>(W, wb);
  k_addt<<<dim3(16, 8, 16), dim3(256), 0, stream>>>(x, pe, out, st);
  k_gemm<<<dim3(8, 12, 16), dim3(256), 0, stream>>>(st, wb, bias, qb, kb, vb);
  k_attn<<<dim3(8, 128), dim3(256), 0, stream>>>(qb, kb, vb, out);
}

// Round 7
// 215.069 us; speedup vs baseline: 1.1373x; 1.1373x over previous
//
#include <hip/hip_runtime.h>
#include <stdint.h>

// MultiHeadAttention2d: x,pe [16][512][1024] f32; W [1536][512]; b [1536]
// out = (x+pe) + MHA(x+pe); 8 heads, dim=64, N=1024.
// Pipeline: k_conv (W->bf16) ; k_addt (residual + s^T bf16) ;
//           k_gemm (QKV, two orientations) ; k_attn (flash attn + residual add)

typedef __attribute__((ext_vector_type(4))) float f32x4;
typedef __attribute__((ext_vector_type(16))) float f32x16;
typedef __attribute__((ext_vector_type(8))) __bf16 bf16x8;
typedef __attribute__((ext_vector_type(8))) short short8;
typedef __attribute__((ext_vector_type(4))) short short4v;
typedef __attribute__((ext_vector_type(4))) int int4v;

#define DEVINL static __device__ __forceinline__

DEVINL unsigned short f2bf(float f) {  // RNE f32 -> bf16 bits
  unsigned u = __builtin_bit_cast(unsigned, f);
  u += 0x7FFFu + ((u >> 16) & 1u);
  return (unsigned short)(u >> 16);
}

DEVINL void gload16(const void* g, const void* lds) {  // async global->LDS, 16B/lane
  __builtin_amdgcn_global_load_lds(
      (const __attribute__((address_space(1))) unsigned int*)(uintptr_t)g,
      (__attribute__((address_space(3))) unsigned int*)(uintptr_t)lds, 16, 0, 0);
}

DEVINL int cvtpk(float lo, float hi) {  // v_cvt_pk_bf16_f32 (no builtin on gfx950)
  int d;
  asm("v_cvt_pk_bf16_f32 %0, %1, %2" : "=v"(d) : "v"(lo), "v"(hi));
  return d;
}

// ---------------- k_conv: W f32 -> bf16 ----------------
__global__ __launch_bounds__(256) void k_conv(const float* __restrict__ Wf,
                                              unsigned short* __restrict__ wbo) {
  const int i = (blockIdx.x * 256 + threadIdx.x) * 4;
  const f32x4 v = *(const f32x4*)(Wf + i);
  short4v t;
  t[0] = (short)f2bf(v[0]); t[1] = (short)f2bf(v[1]);
  t[2] = (short)f2bf(v[2]); t[3] = (short)f2bf(v[3]);
  *(short4v*)(wbo + i) = t;
}

// ---------------- k_addt: s = x+pe -> out (f32) ; s^T bf16 [b][n][c] ----------------
__global__ __launch_bounds__(256) void k_addt(const float* __restrict__ x,
                                              const float* __restrict__ pe,
                                              float* __restrict__ out,
                                              unsigned short* __restrict__ st) {
  __shared__ unsigned short T[64][64];  // bf16 tile [c][n]
  const int b = blockIdx.z, ct = blockIdx.y, nt = blockIdx.x;
  const int tid = threadIdx.x;
  const int cl = tid >> 4, n4 = (tid & 15) * 4;
  const size_t base = ((size_t)b * 512 + ct * 64) * 1024 + nt * 64;
#pragma unroll
  for (int i = 0; i < 4; ++i) {
    const int c = cl + i * 16;
    const size_t idx = base + (size_t)c * 1024 + n4;
    const f32x4 xv = *(const f32x4*)(x + idx);
    const f32x4 pv = *(const f32x4*)(pe + idx);
    const f32x4 s = xv + pv;
    *(f32x4*)(out + idx) = s;  // residual, coalesced
    short4v t;
    t[0] = (short)f2bf(s[0]); t[1] = (short)f2bf(s[1]);
    t[2] = (short)f2bf(s[2]); t[3] = (short)f2bf(s[3]);
    *(short4v*)&T[c][n4] = t;
  }
  __syncthreads();
  const int nl = tid >> 2, cq = tid & 3;
  short8 v0, v1;
#pragma unroll
  for (int j = 0; j < 8; ++j) {
    v0[j] = (short)T[cq * 16 + j][nl];
    v1[j] = (short)T[cq * 16 + 8 + j][nl];
  }
  const size_t so = ((size_t)b * 1024 + nt * 64 + nl) * 512 + ct * 64 + cq * 16;
  *(short8*)(st + so) = v0;
  *(short8*)(st + so + 8) = v1;
}

// ---------------- k_gemm: QKV projection ----------------
// mode0 (blockIdx.y<8):  D = Out^T[n][o], A = s^T [n][c], B^T = W[o][c] (o in [0,1024))
//                        -> q,k stored [b][h][n][d]
// mode1 (blockIdx.y>=8): D = Out[o][n],  A = W[o][c] (o-1024 in [0,512)), B^T = s^T
//                        -> v stored [b][h][d][n]
__global__ __launch_bounds__(256, 2) void k_gemm(const unsigned short* __restrict__ st,
                                                 const unsigned short* __restrict__ wb,
                                                 const float* __restrict__ bias,
                                                 unsigned short* __restrict__ qb,
                                                 unsigned short* __restrict__ kb,
                                                 unsigned short* __restrict__ vb) {
  const int b = blockIdx.z;
  const int mode = (blockIdx.y >= 8);
  const int tile_m = (mode ? (blockIdx.y - 8) : blockIdx.y) * 128;
  const int tile_n = blockIdx.x * 128;
  const unsigned short* Ag;
  const unsigned short* Bg;
  if (!mode) {
    Ag = st + (size_t)b * 524288 + (size_t)tile_m * 512;
    Bg = wb + (size_t)tile_n * 512;
  } else {
    Ag = wb + (size_t)(1024 + tile_m) * 512;
    Bg = st + (size_t)b * 524288 + (size_t)tile_n * 512;
  }
  __shared__ unsigned short As[4096];  // [128][32] bf16
  __shared__ unsigned short Bs[4096];
  const int tid = threadIdx.x, lane = tid & 63, w = tid >> 6;
  const int wrow = w >> 1, wcol = w & 1, lr = lane & 15, g = lane >> 4;
  f32x4 acc[4][4] = {};
  for (int kt = 0; kt < 16; ++kt) {
    __syncthreads();
#pragma unroll
    for (int j = 0; j < 2; ++j) {
      const int D = j * 4096 + w * 1024 + lane * 16;
      const int row = D >> 6, off = D & 63;
      gload16((const char*)Ag + (size_t)row * 1024 + kt * 64 + off,
              (const char*)As + j * 4096 + w * 1024);
      gload16((const char*)Bg + (size_t)row * 1024 + kt * 64 + off,
              (const char*)Bs + j * 4096 + w * 1024);
    }
    __syncthreads();
    bf16x8 a[4], bb[4];
#pragma unroll
    for (int i = 0; i < 4; ++i) {
      a[i]  = *(const bf16x8*)(As + (wrow * 64 + i * 16 + lr) * 32 + g * 8);
      bb[i] = *(const bf16x8*)(Bs + (wcol * 64 + i * 16 + lr) * 32 + g * 8);
    }
#pragma unroll
    for (int i = 0; i < 4; ++i)
#pragma unroll
      for (int jj = 0; jj < 4; ++jj)
        acc[i][jj] = __builtin_amdgcn_mfma_f32_16x16x32_bf16(a[i], bb[jj], acc[i][jj], 0, 0, 0);
  }
  if (!mode) {
#pragma unroll
    for (int jj = 0; jj < 4; ++jj) {
      const int o = tile_n + wcol * 64 + jj * 16 + lr;
      const float bv = bias[o];
      unsigned short* dst = (o < 512) ? qb : kb;
      const size_t rowbase = ((size_t)b * 8 + ((o >> 6) & 7)) * 1024;
      const int d = o & 63;
#pragma unroll
      for (int i = 0; i < 4; ++i) {
        const int n0 = tile_m + wrow * 64 + i * 16 + g * 4;
#pragma unroll
        for (int r = 0; r < 4; ++r)
          dst[(rowbase + n0 + r) * 64 + d] = f2bf(acc[i][jj][r] + bv);
      }
    }
  } else {
#pragma unroll
    for (int i = 0; i < 4; ++i) {
#pragma unroll
      for (int r = 0; r < 4; ++r) {
        const int oh = tile_m + wrow * 64 + i * 16 + g * 4 + r;  // 0..511
        const float bv = bias[1024 + oh];
        const size_t rb = (((size_t)b * 8 + (oh >> 6)) * 64 + (oh & 63)) * 1024;
#pragma unroll
        for (int jj = 0; jj < 4; ++jj) {
          const int n = tile_n + wcol * 64 + jj * 16 + lr;
          vb[rb + n] = f2bf(acc[i][jj][r] + bv);
        }
      }
    }
  }
}

// ---------------- k_attn: flash attention + residual add (in-register P, 32x32 MFMA) ---
// Swapped QK^T: S^T = mfma(K, Q) -> lane owns q-row n = l&31 (lane pair holds the row).
// Swapped PV:   O^T = mfma(V^T, P) -> softmax stats are per-lane scalars.
// Cross-half exchanges use __shfl_xor(...,32) (ds_bpermute) — direction-proof.
// 4 waves x 32 q-rows = 128 q rows per block; KV chunks of 64, double-buffered LDS.
__global__ __launch_bounds__(256, 4) void k_attn(const unsigned short* __restrict__ qb,
                                                 const unsigned short* __restrict__ kb,
                                                 const unsigned short* __restrict__ vb,
                                                 float* __restrict__ out) {
  __shared__ __align__(16) char smem[32768];  // K dbuf 2x8KB @0, V dbuf 2x8KB @16384

  // XCD swizzle: all 8 q-tiles of a (b,h) land on one XCD (K/V L2-resident once).
  const int f = blockIdx.x;               // 1024 blocks, 1024%8==0 -> bijective
  const int bh = (f & 7) * 16 + ((f >> 3) & 15);
  const int qt = f >> 7;

  const int tid = threadIdx.x, lane = tid & 63, w = tid >> 6;
  const int ln = lane & 31, hf = lane >> 5;
  const float F = 0.18033688011112042f;  // (1/sqrt(64)) * log2(e)

  const char* kbase = (const char*)kb + (size_t)bh * 131072;  // [n=1024][d=64] bf16
  const char* vbase = (const char*)vb + (size_t)bh * 131072;  // [d=64][n=1024] bf16

  // Q fragments (B-operand): lane holds Q[n=ln][d = c*16 + hf*8 + j]
  const char* qrow = (const char*)qb + ((size_t)bh * 1024 + qt * 128 + w * 32 + ln) * 128;
  bf16x8 qf[4];
#pragma unroll
  for (int c = 0; c < 4; ++c) qf[c] = *(const bf16x8*)(qrow + c * 32 + hf * 16);

  f32x16 O0 = {}, O1 = {};      // O^T: col n = ln; rows d = rowmap+0 / rowmap+32
  float mF = -__builtin_inff(), lsum = 0.f;

#define STAGE(mt_, buf_)                                                          \
  {                                                                               \
    char* Kd = smem + (buf_) * 8192 + w * 1024;                                   \
    char* Vd = smem + 16384 + (buf_) * 8192 + w * 1024;                           \
    _Pragma("unroll") for (int j = 0; j < 2; ++j) {                               \
      const int D = j * 4096 + w * 1024 + lane * 16;                              \
      const int row = D >> 7, ch = (D >> 4) & 7;                                  \
      const int sw = (ch ^ (row & 7)) * 16;                                       \
      gload16(kbase + (size_t)((mt_) * 64 + row) * 128 + sw, Kd + j * 4096);      \
      gload16(vbase + (size_t)row * 2048 + (mt_) * 128 + sw, Vd + j * 4096);      \
    }                                                                             \
  }

  STAGE(0, 0);
  __syncthreads();
  int buf = 0;
  for (int mt = 0; mt < 16; ++mt) {
    if (mt < 15) STAGE(mt + 1, buf ^ 1);  // prefetch overlaps compute (T3-minimal)
    const char* Kc = smem + buf * 8192;
    const char* Vc = smem + 16384 + buf * 8192;

    // QK^T: s0 = K[m=0..31] x Q, s1 = K[m=32..63] x Q  (D[m][n], col n = ln)
    f32x16 s0 = {}, s1 = {};
#pragma unroll
    for (int c = 0; c < 4; ++c) {
      const int cb = ((c * 2 + hf) ^ (ln & 7)) * 16;  // XOR-swizzled 16B column
      const bf16x8 k0 = *(const bf16x8*)(Kc + ln * 128 + cb);
      s0 = __builtin_amdgcn_mfma_f32_32x32x16_bf16(k0, qf[c], s0, 0, 0, 0);
      const bf16x8 k1 = *(const bf16x8*)(Kc + (32 + ln) * 128 + cb);
      s1 = __builtin_amdgcn_mfma_f32_32x32x16_bf16(k1, qf[c], s1, 0, 0, 0);
    }

    // Row max: in-lane over 32 regs + cross-half shfl_xor (lane pair = one q-row).
    float t = fmaxf(s0[0], s1[0]);
#pragma unroll
    for (int r = 1; r < 16; ++r) t = fmaxf(t, fmaxf(s0[r], s1[r]));
    t = fmaxf(t, __shfl_xor(t, 32));
    const float tF = t * F;
    if (!__all(tF <= mF + 8.f)) {  // T13 defer-max (exp bounded by 2^8)
      const float mN = fmaxf(mF, tF);
      const float al = __builtin_amdgcn_exp2f(mF - mN);
#pragma unroll
      for (int r = 0; r < 16; ++r) { O0[r] *= al; O1[r] *= al; }
      lsum *= al;
      mF = mN;
    }

    // P = exp2(s*F - mF), in place.
#pragma unroll
    for (int r = 0; r < 16; ++r) s0[r] = __builtin_amdgcn_exp2f(fmaf(s0[r], F, -mF));
#pragma unroll
    for (int r = 0; r < 16; ++r) s1[r] = __builtin_amdgcn_exp2f(fmaf(s1[r], F, -mF));

    // Row sum (f32): in-lane tree + cross-half shfl_xor.
    {
      const f32x16 ps = s0 + s1;
      float a0 = (ps[0] + ps[1]) + (ps[2] + ps[3]);
      float a1 = (ps[4] + ps[5]) + (ps[6] + ps[7]);
      float a2 = (ps[8] + ps[9]) + (ps[10] + ps[11]);
      float a3 = (ps[12] + ps[13]) + (ps[14] + ps[15]);
      float sm = (a0 + a1) + (a2 + a3);
      lsum += sm + __shfl_xor(sm, 32);
    }

    // Pack P -> bf16 words; redistribute across the lane pair into B-fragments.
    // C/D row map: lane(ln,hf) reg r holds kv-row (r&3)+8*(r>>2)+4*hf (+32 for s1).
    // B-frag chunk c needs k = c*16 + hf*8 + j. Own regs supply half of each
    // chunk; partner (lane^32) supplies the other half via shfl_xor.
    int c0[8], c1[8];
#pragma unroll
    for (int j = 0; j < 8; ++j) {
      c0[j] = cvtpk(s0[2 * j], s0[2 * j + 1]);
      c1[j] = cvtpk(s1[2 * j], s1[2 * j + 1]);
    }
    int pw[4][4];  // [m-chunk of 16][4 dwords = 8 bf16]
#pragma unroll
    for (int half = 0; half < 2; ++half) {
      const int* cc = half ? c1 : c0;
#pragma unroll
      for (int q = 0; q < 2; ++q) {
        const int b4 = q * 4, ch = half * 2 + q;
        const int p0 = __shfl_xor(cc[b4 + 0], 32);
        const int p1 = __shfl_xor(cc[b4 + 1], 32);
        const int p2 = __shfl_xor(cc[b4 + 2], 32);
        const int p3 = __shfl_xor(cc[b4 + 3], 32);
        pw[ch][0] = hf ? p2 : cc[b4 + 0];
        pw[ch][1] = hf ? p3 : cc[b4 + 1];
        pw[ch][2] = hf ? cc[b4 + 2] : p0;
        pw[ch][3] = hf ? cc[b4 + 3] : p1;
      }
    }

    // PV: O^T += V^T x P  (A = V^T fragment from LDS, B = in-register P fragment)
#pragma unroll
    for (int c = 0; c < 4; ++c) {
      const int4v t4 = {pw[c][0], pw[c][1], pw[c][2], pw[c][3]};
      const bf16x8 pb = __builtin_bit_cast(bf16x8, t4);
      const int cb = ((c * 2 + hf) ^ (ln & 7)) * 16;
      const bf16x8 v0 = *(const bf16x8*)(Vc + ln * 128 + cb);
      O0 = __builtin_amdgcn_mfma_f32_32x32x16_bf16(v0, pb, O0, 0, 0, 0);
      const bf16x8 v1 = *(const bf16x8*)(Vc + (32 + ln) * 128 + cb);
      O1 = __builtin_amdgcn_mfma_f32_32x32x16_bf16(v1, pb, O1, 0, 0, 0);
    }

    __syncthreads();  // compiler emits vmcnt(0): prefetch landed under compute
    buf ^= 1;
  }
#undef STAGE

  // Epilogue: normalize + residual add, coalesced f32 scalar stores (lane pair
  // shares n and lsum; writes disjoint d rows).
  const float inv = 1.0f / lsum;
  float* obase = out + ((size_t)bh * 64) * 1024 + qt * 128 + w * 32 + ln;
#pragma unroll
  for (int r = 0; r < 16; ++r) {
    const int d0 = (r & 3) + 8 * (r >> 2) + 4 * hf;
    obase[(size_t)d0 * 1024] += O0[r] * inv;
    obase[(size_t)(d0 + 32) * 1024] += O1[r] * inv;
  }
}

// ---------------- launcher ----------------
extern "C" void kernel_launch(void* const* d_in, const int* in_sizes, int n_in,
                              void* d_out, int out_size, void* d_ws, size_t ws_size,
                              hipStream_t stream) {
  const float* x    = (const float*)d_in[0];
  const float* pe   = (const float*)d_in[1];
  const float* W    = (const float*)d_in[2];
  const float* bias = (const float*)d_in[3];
  float* out = (float*)d_out;
  char* ws = (char*)d_ws;
  // ws layout (bytes): wb 0..1.5M, st @2M (16M), q @18M, k @34M, v @50M (16M each)
  unsigned short* wb = (unsigned short*)(ws);
  unsigned short* st = (unsigned short*)(ws + ((size_t)2 << 20));
  unsigned short* qb = (unsigned short*)(ws + ((size_t)18 << 20));
  unsigned short* kb = (unsigned short*)(ws + ((size_t)34 << 20));
  unsigned short* vb = (unsigned short*)(ws + ((size_t)50 << 20));

  k_conv<<<dim3(768), dim3(256), 0, stream>>>(W, wb);
  k_addt<<<dim3(16, 8, 16), dim3(256), 0, stream>>>(x, pe, out, st);
  k_gemm<<<dim3(8, 12, 16), dim3(256), 0, stream>>>(st, wb, bias, qb, kb, vb);
  k_attn<<<dim3(1024), dim3(256), 0, stream>>>(qb, kb, vb, out);
}

// Round 11
// 209.592 us; speedup vs baseline: 1.1670x; 1.0261x over previous
//
#include <hip/hip_runtime.h>
#include <stdint.h>

// MultiHeadAttention2d: x,pe [16][512][1024] f32; W [1536][512]; b [1536]
// out = (x+pe) + MHA(x+pe); 8 heads, dim=64, N=1024.
// Pipeline: k_conv (W->bf16) ; k_addt (residual + s^T bf16) ;
//           k_gemm (QKV, two orientations) ; k_attn (flash attn + residual add)

typedef __attribute__((ext_vector_type(4))) float f32x4;
typedef __attribute__((ext_vector_type(16))) float f32x16;
typedef __attribute__((ext_vector_type(8))) __bf16 bf16x8;
typedef __attribute__((ext_vector_type(8))) short short8;
typedef __attribute__((ext_vector_type(4))) short short4v;
typedef __attribute__((ext_vector_type(4))) int int4v;

#define DEVINL static __device__ __forceinline__

DEVINL unsigned short f2bf(float f) {  // RNE f32 -> bf16 bits
  unsigned u = __builtin_bit_cast(unsigned, f);
  u += 0x7FFFu + ((u >> 16) & 1u);
  return (unsigned short)(u >> 16);
}

DEVINL void gload16(const void* g, const void* lds) {  // async global->LDS, 16B/lane
  __builtin_amdgcn_global_load_lds(
      (const __attribute__((address_space(1))) unsigned int*)(uintptr_t)g,
      (__attribute__((address_space(3))) unsigned int*)(uintptr_t)lds, 16, 0, 0);
}

DEVINL int cvtpk(float lo, float hi) {  // v_cvt_pk_bf16_f32 (no builtin on gfx950)
  int d;
  asm("v_cvt_pk_bf16_f32 %0, %1, %2" : "=v"(d) : "v"(lo), "v"(hi));
  return d;
}

DEVINL void pl32swap(int& a, int& b) {  // a.hi lanes <-> b.lo lanes (in place)
  asm("v_permlane32_swap_b32 %0, %1" : "+v"(a), "+v"(b));
}

// ---------------- k_conv: W f32 -> bf16 ----------------
__global__ __launch_bounds__(256) void k_conv(const float* __restrict__ Wf,
                                              unsigned short* __restrict__ wbo) {
  const int i = (blockIdx.x * 256 + threadIdx.x) * 4;
  const f32x4 v = *(const f32x4*)(Wf + i);
  short4v t;
  t[0] = (short)f2bf(v[0]); t[1] = (short)f2bf(v[1]);
  t[2] = (short)f2bf(v[2]); t[3] = (short)f2bf(v[3]);
  *(short4v*)(wbo + i) = t;
}

// ---------------- k_addt: s = x+pe -> out (f32) ; s^T bf16 [b][n][c] ----------------
__global__ __launch_bounds__(256) void k_addt(const float* __restrict__ x,
                                              const float* __restrict__ pe,
                                              float* __restrict__ out,
                                              unsigned short* __restrict__ st) {
  __shared__ unsigned short T[64][64];  // bf16 tile [c][n]
  const int b = blockIdx.z, ct = blockIdx.y, nt = blockIdx.x;
  const int tid = threadIdx.x;
  const int cl = tid >> 4, n4 = (tid & 15) * 4;
  const size_t base = ((size_t)b * 512 + ct * 64) * 1024 + nt * 64;
#pragma unroll
  for (int i = 0; i < 4; ++i) {
    const int c = cl + i * 16;
    const size_t idx = base + (size_t)c * 1024 + n4;
    const f32x4 xv = *(const f32x4*)(x + idx);
    const f32x4 pv = *(const f32x4*)(pe + idx);
    const f32x4 s = xv + pv;
    *(f32x4*)(out + idx) = s;  // residual, coalesced
    short4v t;
    t[0] = (short)f2bf(s[0]); t[1] = (short)f2bf(s[1]);
    t[2] = (short)f2bf(s[2]); t[3] = (short)f2bf(s[3]);
    *(short4v*)&T[c][n4] = t;
  }
  __syncthreads();
  const int nl = tid >> 2, cq = tid & 3;
  short8 v0, v1;
#pragma unroll
  for (int j = 0; j < 8; ++j) {
    v0[j] = (short)T[cq * 16 + j][nl];
    v1[j] = (short)T[cq * 16 + 8 + j][nl];
  }
  const size_t so = ((size_t)b * 1024 + nt * 64 + nl) * 512 + ct * 64 + cq * 16;
  *(short8*)(st + so) = v0;
  *(short8*)(st + so + 8) = v1;
}

// ---------------- k_gemm: QKV projection ----------------
// 1D grid 1536, XCD-chunked decode: all 8 tile_n blocks of one (tile_m,batch)
// land on ONE XCD so the A-tile is fetched once per XCD, not 8x.
// mode0 (by<8):  D = Out^T[n][o], A = s^T [n][c], B^T = W[o][c] -> q,k [b][h][n][d]
// mode1 (by>=8): D = Out[o][n],  A = W[o][c], B^T = s^T         -> v   [b][h][d][n]
__global__ __launch_bounds__(256, 4) void k_gemm(const unsigned short* __restrict__ st,
                                                 const unsigned short* __restrict__ wb,
                                                 const float* __restrict__ bias,
                                                 unsigned short* __restrict__ qb,
                                                 unsigned short* __restrict__ kb,
                                                 unsigned short* __restrict__ vb) {
  const int fid = blockIdx.x;            // 0..1535
  const int xcd = fid & 7, s = fid >> 3; // consecutive ids round-robin XCDs
  const int t = xcd * 24 + (s >> 3);     // (by,b) group: 192 total, 24 per XCD
  const int bx = s & 7;                  // tile_n index 0..7
  const int by = t % 12;                 // 0..11 (mode0: 0..7, mode1: 8..11)
  const int b = t / 12;                  // batch 0..15
  const int mode = (by >= 8);
  const int tile_m = (mode ? (by - 8) : by) * 128;
  const int tile_n = bx * 128;
  const unsigned short* Ag;
  const unsigned short* Bg;
  if (!mode) {
    Ag = st + (size_t)b * 524288 + (size_t)tile_m * 512;
    Bg = wb + (size_t)tile_n * 512;
  } else {
    Ag = wb + (size_t)(1024 + tile_m) * 512;
    Bg = st + (size_t)b * 524288 + (size_t)tile_n * 512;
  }
  __shared__ unsigned short As[4096];  // [128][32] bf16
  __shared__ unsigned short Bs[4096];
  const int tid = threadIdx.x, lane = tid & 63, w = tid >> 6;
  const int wrow = w >> 1, wcol = w & 1, lr = lane & 15, g = lane >> 4;
  f32x4 acc[4][4] = {};
  for (int kt = 0; kt < 16; ++kt) {
    __syncthreads();
#pragma unroll
    for (int j = 0; j < 2; ++j) {
      const int D = j * 4096 + w * 1024 + lane * 16;
      const int row = D >> 6, off = D & 63;
      gload16((const char*)Ag + (size_t)row * 1024 + kt * 64 + off,
              (const char*)As + j * 4096 + w * 1024);
      gload16((const char*)Bg + (size_t)row * 1024 + kt * 64 + off,
              (const char*)Bs + j * 4096 + w * 1024);
    }
    __syncthreads();
    bf16x8 a[4], bb[4];
#pragma unroll
    for (int i = 0; i < 4; ++i) {
      a[i]  = *(const bf16x8*)(As + (wrow * 64 + i * 16 + lr) * 32 + g * 8);
      bb[i] = *(const bf16x8*)(Bs + (wcol * 64 + i * 16 + lr) * 32 + g * 8);
    }
#pragma unroll
    for (int i = 0; i < 4; ++i)
#pragma unroll
      for (int jj = 0; jj < 4; ++jj)
        acc[i][jj] = __builtin_amdgcn_mfma_f32_16x16x32_bf16(a[i], bb[jj], acc[i][jj], 0, 0, 0);
  }
  if (!mode) {
#pragma unroll
    for (int jj = 0; jj < 4; ++jj) {
      const int o = tile_n + wcol * 64 + jj * 16 + lr;
      const float bv = bias[o];
      unsigned short* dst = (o < 512) ? qb : kb;
      const size_t rowbase = ((size_t)b * 8 + ((o >> 6) & 7)) * 1024;
      const int d = o & 63;
#pragma unroll
      for (int i = 0; i < 4; ++i) {
        const int n0 = tile_m + wrow * 64 + i * 16 + g * 4;
#pragma unroll
        for (int r = 0; r < 4; ++r)
          dst[(rowbase + n0 + r) * 64 + d] = f2bf(acc[i][jj][r] + bv);
      }
    }
  } else {
#pragma unroll
    for (int i = 0; i < 4; ++i) {
#pragma unroll
      for (int r = 0; r < 4; ++r) {
        const int oh = tile_m + wrow * 64 + i * 16 + g * 4 + r;  // 0..511
        const float bv = bias[1024 + oh];
        const size_t rb = (((size_t)b * 8 + (oh >> 6)) * 64 + (oh & 63)) * 1024;
#pragma unroll
        for (int jj = 0; jj < 4; ++jj) {
          const int n = tile_n + wcol * 64 + jj * 16 + lr;
          vb[rb + n] = f2bf(acc[i][jj][r] + bv);
        }
      }
    }
  }
}

// ---------------- k_attn: flash attention + residual add (in-register P, 32x32 MFMA) ---
// Swapped QK^T: S^T = mfma(K, Q) -> lane owns q-row n = l&31 (lane pair holds the row).
// Swapped PV:   O^T = mfma(V^T, P) -> softmax stats are per-lane scalars.
// max/sum via shfl_xor(32); P redistribution via v_permlane32_swap_b32 (VALU, T12).
// 4 waves x 32 q-rows = 128 q rows per block; KV chunks of 64, double-buffered LDS.
__global__ __launch_bounds__(256, 4) void k_attn(const unsigned short* __restrict__ qb,
                                                 const unsigned short* __restrict__ kb,
                                                 const unsigned short* __restrict__ vb,
                                                 float* __restrict__ out) {
  __shared__ __align__(16) char smem[32768];  // K dbuf 2x8KB @0, V dbuf 2x8KB @16384

  // XCD swizzle: all 8 q-tiles of a (b,h) land on one XCD (K/V L2-resident once).
  const int f = blockIdx.x;               // 1024 blocks, 1024%8==0 -> bijective
  const int bh = (f & 7) * 16 + ((f >> 3) & 15);
  const int qt = f >> 7;

  const int tid = threadIdx.x, lane = tid & 63, w = tid >> 6;
  const int ln = lane & 31, hf = lane >> 5;
  const float F = 0.18033688011112042f;  // (1/sqrt(64)) * log2(e)

  const char* kbase = (const char*)kb + (size_t)bh * 131072;  // [n=1024][d=64] bf16
  const char* vbase = (const char*)vb + (size_t)bh * 131072;  // [d=64][n=1024] bf16

  // Q fragments (B-operand): lane holds Q[n=ln][d = c*16 + hf*8 + j]
  const char* qrow = (const char*)qb + ((size_t)bh * 1024 + qt * 128 + w * 32 + ln) * 128;
  bf16x8 qf[4];
#pragma unroll
  for (int c = 0; c < 4; ++c) qf[c] = *(const bf16x8*)(qrow + c * 32 + hf * 16);

  f32x16 O0 = {}, O1 = {};      // O^T: col n = ln; rows d = rowmap+0 / rowmap+32
  float mF = -__builtin_inff(), lsum = 0.f;

#define STAGE(mt_, buf_)                                                          \
  {                                                                               \
    char* Kd = smem + (buf_) * 8192 + w * 1024;                                   \
    char* Vd = smem + 16384 + (buf_) * 8192 + w * 1024;                           \
    _Pragma("unroll") for (int j = 0; j < 2; ++j) {                               \
      const int D = j * 4096 + w * 1024 + lane * 16;                              \
      const int row = D >> 7, ch = (D >> 4) & 7;                                  \
      const int sw = (ch ^ (row & 7)) * 16;                                       \
      gload16(kbase + (size_t)((mt_) * 64 + row) * 128 + sw, Kd + j * 4096);      \
      gload16(vbase + (size_t)row * 2048 + (mt_) * 128 + sw, Vd + j * 4096);      \
    }                                                                             \
  }

  STAGE(0, 0);
  __syncthreads();
  int buf = 0;
  for (int mt = 0; mt < 16; ++mt) {
    if (mt < 15) STAGE(mt + 1, buf ^ 1);  // prefetch overlaps compute (T3-minimal)
    const char* Kc = smem + buf * 8192;
    const char* Vc = smem + 16384 + buf * 8192;

    // QK^T: s0 = K[m=0..31] x Q, s1 = K[m=32..63] x Q  (D[m][n], col n = ln)
    f32x16 s0 = {}, s1 = {};
#pragma unroll
    for (int c = 0; c < 4; ++c) {
      const int cb = ((c * 2 + hf) ^ (ln & 7)) * 16;  // XOR-swizzled 16B column
      const bf16x8 k0 = *(const bf16x8*)(Kc + ln * 128 + cb);
      s0 = __builtin_amdgcn_mfma_f32_32x32x16_bf16(k0, qf[c], s0, 0, 0, 0);
      const bf16x8 k1 = *(const bf16x8*)(Kc + (32 + ln) * 128 + cb);
      s1 = __builtin_amdgcn_mfma_f32_32x32x16_bf16(k1, qf[c], s1, 0, 0, 0);
    }

    // Row max: in-lane over 32 regs + cross-half shfl_xor (lane pair = one q-row).
    float t = fmaxf(s0[0], s1[0]);
#pragma unroll
    for (int r = 1; r < 16; ++r) t = fmaxf(t, fmaxf(s0[r], s1[r]));
    t = fmaxf(t, __shfl_xor(t, 32));
    const float tF = t * F;
    if (!__all(tF <= mF + 8.f)) {  // T13 defer-max (exp bounded by 2^8)
      const float mN = fmaxf(mF, tF);
      const float al = __builtin_amdgcn_exp2f(mF - mN);
#pragma unroll
      for (int r = 0; r < 16; ++r) { O0[r] *= al; O1[r] *= al; }
      lsum *= al;
      mF = mN;
    }

    // P = exp2(s*F - mF), in place.
#pragma unroll
    for (int r = 0; r < 16; ++r) s0[r] = __builtin_amdgcn_exp2f(fmaf(s0[r], F, -mF));
#pragma unroll
    for (int r = 0; r < 16; ++r) s1[r] = __builtin_amdgcn_exp2f(fmaf(s1[r], F, -mF));

    // Row sum (f32): in-lane tree + cross-half shfl_xor.
    {
      const f32x16 ps = s0 + s1;
      float a0 = (ps[0] + ps[1]) + (ps[2] + ps[3]);
      float a1 = (ps[4] + ps[5]) + (ps[6] + ps[7]);
      float a2 = (ps[8] + ps[9]) + (ps[10] + ps[11]);
      float a3 = (ps[12] + ps[13]) + (ps[14] + ps[15]);
      float sm = (a0 + a1) + (a2 + a3);
      lsum += sm + __shfl_xor(sm, 32);
    }

    // Pack P -> bf16 words; redistribute across the lane pair into B-fragments
    // via permlane32_swap (T12): after swap(cc[q*4+t], cc[q*4+t+2]) the hf0 lane
    // holds kv-rows base..base+7 and hf1 holds base+8..base+15 = B[k=hf*8+j].
    // (Same mapping as the round-6 shfl version, on the VALU pipe, 8 ops not 16.)
    int c0[8], c1[8];
#pragma unroll
    for (int j = 0; j < 8; ++j) {
      c0[j] = cvtpk(s0[2 * j], s0[2 * j + 1]);
      c1[j] = cvtpk(s1[2 * j], s1[2 * j + 1]);
    }
    int pw[4][4];  // [m-chunk of 16][4 dwords = 8 bf16]
#pragma unroll
    for (int half = 0; half < 2; ++half) {
      int* cc = half ? c1 : c0;
#pragma unroll
      for (int q = 0; q < 2; ++q) {
        const int b4 = q * 4, ch = half * 2 + q;
        pl32swap(cc[b4 + 0], cc[b4 + 2]);
        pl32swap(cc[b4 + 1], cc[b4 + 3]);
        pw[ch][0] = cc[b4 + 0]; pw[ch][1] = cc[b4 + 1];
        pw[ch][2] = cc[b4 + 2]; pw[ch][3] = cc[b4 + 3];
      }
    }

    // PV: O^T += V^T x P  (A = V^T fragment from LDS, B = in-register P fragment)
#pragma unroll
    for (int c = 0; c < 4; ++c) {
      const int4v t4 = {pw[c][0], pw[c][1], pw[c][2], pw[c][3]};
      const bf16x8 pb = __builtin_bit_cast(bf16x8, t4);
      const int cb = ((c * 2 + hf) ^ (ln & 7)) * 16;
      const bf16x8 v0 = *(const bf16x8*)(Vc + ln * 128 + cb);
      O0 = __builtin_amdgcn_mfma_f32_32x32x16_bf16(v0, pb, O0, 0, 0, 0);
      const bf16x8 v1 = *(const bf16x8*)(Vc + (32 + ln) * 128 + cb);
      O1 = __builtin_amdgcn_mfma_f32_32x32x16_bf16(v1, pb, O1, 0, 0, 0);
    }

    __syncthreads();  // compiler emits vmcnt(0): prefetch landed under compute
    buf ^= 1;
  }
#undef STAGE

  // Epilogue: normalize + residual add, coalesced f32 scalar stores (lane pair
  // shares n and lsum; writes disjoint d rows).
  const float inv = 1.0f / lsum;
  float* obase = out + ((size_t)bh * 64) * 1024 + qt * 128 + w * 32 + ln;
#pragma unroll
  for (int r = 0; r < 16; ++r) {
    const int d0 = (r & 3) + 8 * (r >> 2) + 4 * hf;
    obase[(size_t)d0 * 1024] += O0[r] * inv;
    obase[(size_t)(d0 + 32) * 1024] += O1[r] * inv;
  }
}

// ---------------- launcher ----------------
extern "C" void kernel_launch(void* const* d_in, const int* in_sizes, int n_in,
                              void* d_out, int out_size, void* d_ws, size_t ws_size,
                              hipStream_t stream) {
  const float* x    = (const float*)d_in[0];
  const float* pe   = (const float*)d_in[1];
  const float* W    = (const float*)d_in[2];
  const float* bias = (const float*)d_in[3];
  float* out = (float*)d_out;
  char* ws = (char*)d_ws;
  // ws layout (bytes): wb 0..1.5M, st @2M (16M), q @18M, k @34M, v @50M (16M each)
  unsigned short* wb = (unsigned short*)(ws);
  unsigned short* st = (unsigned short*)(ws + ((size_t)2 << 20));
  unsigned short* qb = (unsigned short*)(ws + ((size_t)18 << 20));
  unsigned short* kb = (unsigned short*)(ws + ((size_t)34 << 20));
  unsigned short* vb = (unsigned short*)(ws + ((size_t)50 << 20));

  k_conv<<<dim3(768), dim3(256), 0, stream>>>(W, wb);
  k_addt<<<dim3(16, 8, 16), dim3(256), 0, stream>>>(x, pe, out, st);
  k_gemm<<<dim3(1536), dim3(256), 0, stream>>>(st, wb, bias, qb, kb, vb);
  k_attn<<<dim3(1024), dim3(256), 0, stream>>>(qb, kb, vb, out);
}